// Round 1
// baseline (724.652 us; speedup 1.0000x reference)
//
#include <hip/hip_runtime.h>
#include <math.h>

#define NCLS  100
#define ITERS 100
#define NPAD  128   // LDS slots (64 lanes x 2)

#if __has_builtin(__builtin_amdgcn_rcpf)
__device__ __forceinline__ float fast_rcp(float x) { return __builtin_amdgcn_rcpf(x); }
#else
__device__ __forceinline__ float fast_rcp(float x) { return 1.0f / x; }
#endif

__device__ __forceinline__ float wave_sum(float v) {
#pragma unroll
    for (int m = 32; m > 0; m >>= 1) v += __shfl_xor(v, m, 64);
    return v;
}
__device__ __forceinline__ float wave_max(float v) {
#pragma unroll
    for (int m = 32; m > 0; m >>= 1) v = fmaxf(v, __shfl_xor(v, m, 64));
    return v;
}

// dot of the lane's two adjacent K-rows (register window krr[0..100]) with
// the 100-float vector in LDS (broadcast reads). Row i0 uses krr[j+1],
// row i0+1 uses krr[j].
#define MATVEC(dst0, dst1, vptr)                                   \
    {                                                              \
        float t0a = 0.f, t0b = 0.f, t1a = 0.f, t1b = 0.f;          \
        _Pragma("unroll")                                          \
        for (int j = 0; j < NCLS; j += 4) {                        \
            float4 b4 = *(const float4*)((vptr) + j);              \
            t0a = fmaf(krr[j + 1], b4.x, t0a);                     \
            t1a = fmaf(krr[j + 0], b4.x, t1a);                     \
            t0b = fmaf(krr[j + 2], b4.y, t0b);                     \
            t1b = fmaf(krr[j + 1], b4.y, t1b);                     \
            t0a = fmaf(krr[j + 3], b4.z, t0a);                     \
            t1a = fmaf(krr[j + 2], b4.z, t1a);                     \
            t0b = fmaf(krr[j + 4], b4.w, t0b);                     \
            t1b = fmaf(krr[j + 3], b4.w, t1b);                     \
        }                                                          \
        dst0 = t0a + t0b;                                          \
        dst1 = t1a + t1b;                                          \
    }

extern "C" __global__ void sk_zero_out(float* out) { out[0] = 0.0f; }

extern "C" __global__ void __launch_bounds__(64)
sk_sinkhorn(const float* __restrict__ pred, const int* __restrict__ target,
            float* __restrict__ out, int rows)
{
    __shared__ float4 vaS[NPAD / 4], vbS[NPAD / 4], vsS[NPAD / 4];
    float* va = (float*)vaS;
    float* vb = (float*)vbS;
    float* vs = (float*)vsS;

    const int r  = blockIdx.x;
    const int l  = threadIdx.x;
    const int i0 = 2 * l;
    const int i1 = i0 + 1;
    const bool active = (i0 < NCLS);

    // ---- marginals: mu = normalize(softmax(pred_row) + STAB) ----
    const float* prow = pred + (size_t)r * NCLS;
    float p0 = active ? prow[i0] : -3.4e38f;
    float p1 = active ? prow[i1] : -3.4e38f;
    float mx = wave_max(fmaxf(p0, p1));
    float e0 = active ? expf(p0 - mx) : 0.0f;
    float e1 = active ? expf(p1 - mx) : 0.0f;
    float S    = wave_sum(e0 + e1);
    float invS = 1.0f / S;
    float mur0 = active ? (e0 * invS + 1e-6f) : 0.0f;
    float mur1 = active ? (e1 * invS + 1e-6f) : 0.0f;
    float Smu  = wave_sum(mur0 + mur1);
    float invM = 1.0f / Smu;
    float mu0 = mur0 * invM, mu1 = mur1 * invM;

    // ---- nu = normalize(one_hot(target) + STAB) ----
    int   tgt = target[r];
    float nr0 = active ? (((i0 == tgt) ? 1.0f : 0.0f) + 1e-6f) : 0.0f;
    float nr1 = active ? (((i1 == tgt) ? 1.0f : 0.0f) + 1e-6f) : 0.0f;
    float Snu  = wave_sum(nr0 + nr1);
    float invN = 1.0f / Snu;
    float nu0 = nr0 * invN, nu1 = nr1 * invN;

    // ---- K-row register window (Toeplitz): krr[t] = exp(-10*C) at d=i0+1-t ----
    // C_ij = (i-j)^2 / 9801 (cmax = 99^2), log_K = -C/EPS exactly (never clipped).
    float krr[NCLS + 1];
#pragma unroll
    for (int t = 0; t <= NCLS; ++t) {
        int   dd = i1 - t;
        float c  = (float)(dd * dd) * (1.0f / 9801.0f);
        krr[t]   = expf(-10.0f * c);
    }

    // ---- Sinkhorn scaling iterations, exp domain: a=mu/(Kb), b=nu/(Ka) ----
    float a0 = 0.f, a1 = 0.f, b0 = 1.0f, b1 = 1.0f;
    ((float2*)vb)[l] = make_float2(b0, b1);
    __syncthreads();

    for (int it = 0; it < ITERS; ++it) {
        float t0, t1;
        MATVEC(t0, t1, vb);
        a0 = mu0 * fast_rcp(t0);
        a1 = mu1 * fast_rcp(t1);
        ((float2*)va)[l] = make_float2(a0, a1);
        __syncthreads();

        float s0, s1;
        MATVEC(s0, s1, va);
        b0 = nu0 * fast_rcp(s0);
        b1 = nu1 * fast_rcp(s1);
        ((float2*)vb)[l] = make_float2(b0, b1);
        __syncthreads();
    }

    // ---- epilogue: P = a K b + STAB, row-renorm to mu, col-renorm to nu ----
    // rowsum_i = a_i*(Kb)_i + n*STAB ; sc_i = mu_i/rowsum_i ; a'_i = a_i*sc_i
    float t0, t1;
    MATVEC(t0, t1, vb);
    float row0 = fmaf(a0, t0, (float)NCLS * 1e-6f);
    float row1 = fmaf(a1, t1, (float)NCLS * 1e-6f);
    float sc0 = active ? mu0 * fast_rcp(row0) : 0.0f;
    float sc1 = active ? mu1 * fast_rcp(row1) : 0.0f;
    float ap0 = a0 * sc0, ap1 = a1 * sc1;
    ((float2*)va)[l] = make_float2(ap0, ap1);
    ((float2*)vs)[l] = make_float2(sc0, sc1);
    __syncthreads();
    float Ssum = wave_sum(sc0 + sc1);

    // q_j=(K a')_j, m_j=((K.C) a')_j, cs_j=(C s)_j for the lane's rows j=i0,i1
    float q0 = 0.f, q1 = 0.f, mm0 = 0.f, mm1 = 0.f, cs0 = 0.f, cs1 = 0.f;
    const float fi0 = (float)i0;
#pragma unroll
    for (int j = 0; j < NCLS; j += 4) {
        float4 a4 = *(const float4*)(va + j);
        float4 s4 = *(const float4*)(vs + j);
#define EP(k, AV, SV)                                                  \
        {                                                              \
            float kk0 = krr[j + k + 1], kk1 = krr[j + k];              \
            float d0  = fi0 - (float)(j + k);                          \
            float d1  = d0 + 1.0f;                                     \
            float c0  = d0 * d0 * (1.0f / 9801.0f);                    \
            float c1  = d1 * d1 * (1.0f / 9801.0f);                    \
            q0  = fmaf(kk0, AV, q0);                                   \
            q1  = fmaf(kk1, AV, q1);                                   \
            mm0 = fmaf(kk0 * c0, AV, mm0);                             \
            mm1 = fmaf(kk1 * c1, AV, mm1);                             \
            cs0 = fmaf(c0, SV, cs0);                                   \
            cs1 = fmaf(c1, SV, cs1);                                   \
        }
        EP(0, a4.x, s4.x)
        EP(1, a4.y, s4.y)
        EP(2, a4.z, s4.z)
        EP(3, a4.w, s4.w)
#undef EP
    }

    // colsum_j = b_j*q_j + STAB*sum(sc) ; cost = sum_j nu_j/colsum_j * (b_j*m_j + STAB*cs_j)
    float z = 0.0f;
    if (active) {
        float col0 = fmaf(b0, q0, 1e-6f * Ssum);
        float col1 = fmaf(b1, q1, 1e-6f * Ssum);
        float in0  = fmaf(b0, mm0, 1e-6f * cs0);
        float in1  = fmaf(b1, mm1, 1e-6f * cs1);
        z = nu0 * fast_rcp(col0) * in0 + nu1 * fast_rcp(col1) * in1;
    }
    float rc = wave_sum(z);
    if (l == 0) atomicAdd(out, rc / (float)rows);
}

extern "C" void kernel_launch(void* const* d_in, const int* in_sizes, int n_in,
                              void* d_out, int out_size, void* d_ws, size_t ws_size,
                              hipStream_t stream)
{
    const float* pred   = (const float*)d_in[0];
    const int*   target = (const int*)d_in[1];
    float*       out    = (float*)d_out;
    const int    rows   = in_sizes[0] / NCLS;   // 4096

    hipLaunchKernelGGL(sk_zero_out, dim3(1), dim3(1), 0, stream, out);
    hipLaunchKernelGGL(sk_sinkhorn, dim3(rows), dim3(64), 0, stream,
                       pred, target, out, rows);
}

// Round 2
// 427.090 us; speedup vs baseline: 1.6967x; 1.6967x over previous
//
#include <hip/hip_runtime.h>
#include <math.h>

#define NCLS  100
#define ITERS 100

#if __has_builtin(__builtin_amdgcn_rcpf)
__device__ __forceinline__ float fast_rcp(float x) { return __builtin_amdgcn_rcpf(x); }
#else
__device__ __forceinline__ float fast_rcp(float x) { return 1.0f / x; }
#endif

// wave-register broadcast: value of `v` in lane `l` (uniform across wave).
__device__ __forceinline__ float rlane(float v, int l) {
    return __int_as_float(__builtin_amdgcn_readlane(__float_as_int(v), l));
}

__device__ __forceinline__ float wave_sum(float v) {
#pragma unroll
    for (int m = 32; m > 0; m >>= 1) v += __shfl_xor(v, m, 64);
    return v;
}
__device__ __forceinline__ float wave_max(float v) {
#pragma unroll
    for (int m = 32; m > 0; m >>= 1) v = fmaxf(v, __shfl_xor(v, m, 64));
    return v;
}

// t{0,1} = (K x)_{i0,i1} where x is distributed: lane p holds x[2p] in s0,
// x[2p+1] in s1. Broadcast via v_readlane (VALU pipe) -> zero LDS, zero
// barriers. K row window lives in per-lane registers krr[0..100],
// krr[t] = w(i1 - t), w symmetric; K[i0][j]=krr[j+1], K[i1][j]=krr[j].
#define MATVEC(dst0, dst1, s0, s1)                                  \
    {                                                               \
        float t0a = 0.f, t0b = 0.f, t1a = 0.f, t1b = 0.f;           \
        _Pragma("unroll")                                           \
        for (int j = 0; j < NCLS; j += 2) {                         \
            float blo = rlane(s0, j >> 1);                          \
            float bhi = rlane(s1, j >> 1);                          \
            t0a = fmaf(krr[j + 1], blo, t0a);                       \
            t1a = fmaf(krr[j + 0], blo, t1a);                       \
            t0b = fmaf(krr[j + 2], bhi, t0b);                       \
            t1b = fmaf(krr[j + 1], bhi, t1b);                       \
        }                                                           \
        dst0 = t0a + t0b;                                           \
        dst1 = t1a + t1b;                                           \
    }

extern "C" __global__ void sk_zero_out(float* out) { out[0] = 0.0f; }

extern "C" __global__ void __launch_bounds__(64, 2)
sk_sinkhorn(const float* __restrict__ pred, const int* __restrict__ target,
            float* __restrict__ out, int rows)
{
    const int r  = blockIdx.x;
    const int l  = threadIdx.x;
    const int i0 = 2 * l;
    const int i1 = i0 + 1;
    const bool active = (i0 < NCLS);

    // ---- marginals: mu = normalize(softmax(pred_row) + STAB) ----
    const float* prow = pred + (size_t)r * NCLS;
    float p0 = active ? prow[i0] : -3.4e38f;
    float p1 = active ? prow[i1] : -3.4e38f;
    float mx = wave_max(fmaxf(p0, p1));
    float e0 = active ? expf(p0 - mx) : 0.0f;
    float e1 = active ? expf(p1 - mx) : 0.0f;
    float S    = wave_sum(e0 + e1);
    float invS = 1.0f / S;
    float mur0 = active ? (e0 * invS + 1e-6f) : 0.0f;
    float mur1 = active ? (e1 * invS + 1e-6f) : 0.0f;
    float Smu  = wave_sum(mur0 + mur1);
    float invM = 1.0f / Smu;
    float mu0 = mur0 * invM, mu1 = mur1 * invM;

    // ---- nu = normalize(one_hot(target) + STAB) ----
    int   tgt = target[r];
    float nr0 = active ? (((i0 == tgt) ? 1.0f : 0.0f) + 1e-6f) : 0.0f;
    float nr1 = active ? (((i1 == tgt) ? 1.0f : 0.0f) + 1e-6f) : 0.0f;
    float Snu  = wave_sum(nr0 + nr1);
    float invN = 1.0f / Snu;
    float nu0 = nr0 * invN, nu1 = nr1 * invN;

    // ---- K-row register window (Toeplitz): krr[t] = exp(-10*C), C=(d^2)/9801 ----
    float krr[NCLS + 1];
#pragma unroll
    for (int t = 0; t <= NCLS; ++t) {
        int   dd = i1 - t;
        float c  = (float)(dd * dd) * (1.0f / 9801.0f);
        krr[t]   = expf(-10.0f * c);
    }

    // ---- Sinkhorn scaling, exp domain: a = mu/(K b), b = nu/(K a) ----
    // Entirely in registers; inactive lanes carry mu=nu=0 -> a=0, b never read.
    float a0 = 0.f, a1 = 0.f, b0 = 1.0f, b1 = 1.0f;
#pragma unroll 1
    for (int it = 0; it < ITERS; ++it) {
        float t0, t1;
        MATVEC(t0, t1, b0, b1);
        a0 = mu0 * fast_rcp(t0);
        a1 = mu1 * fast_rcp(t1);
        float s0, s1;
        MATVEC(s0, s1, a0, a1);
        b0 = nu0 * fast_rcp(s0);
        b1 = nu1 * fast_rcp(s1);
    }

    // ---- epilogue: P = a K b + STAB, renorm rows to mu, cols to nu ----
    // rowsum_i = a_i*(Kb)_i + n*STAB ; scl_i = mu_i/rowsum_i ; a'_i = a_i*scl_i
    float t0, t1;
    MATVEC(t0, t1, b0, b1);
    float row0 = fmaf(a0, t0, (float)NCLS * 1e-6f);
    float row1 = fmaf(a1, t1, (float)NCLS * 1e-6f);
    float scl0 = mu0 * fast_rcp(row0);   // inactive: mu=0 -> 0
    float scl1 = mu1 * fast_rcp(row1);
    float ap0 = a0 * scl0, ap1 = a1 * scl1;
    float Ssum = wave_sum(scl0 + scl1);

    // q_j=(K a')_j, mm_j=((K.C) a')_j, cs_j=(C scl)_j at j = i0, i1
    float q0 = 0.f, q1 = 0.f, mm0 = 0.f, mm1 = 0.f, cs0 = 0.f, cs1 = 0.f;
    const float fi0 = (float)i0;
    const float inv = 1.0f / 9801.0f;
#pragma unroll
    for (int j = 0; j < NCLS; j += 2) {
        float alo = rlane(ap0,  j >> 1);
        float ahi = rlane(ap1,  j >> 1);
        float slo = rlane(scl0, j >> 1);
        float shi = rlane(scl1, j >> 1);
        float d0 = fi0 - (float)j;
        float em = (d0 - 1.0f) * (d0 - 1.0f) * inv;  // C(i0, j+1)
        float e0c = d0 * d0 * inv;                   // C(i0,j) = C(i1,j+1)
        float ep = (d0 + 1.0f) * (d0 + 1.0f) * inv;  // C(i1, j)
        float klo0 = krr[j + 1], khi0 = krr[j + 2];  // K[i0][j], K[i0][j+1]
        float klo1 = krr[j + 0], khi1 = krr[j + 1];  // K[i1][j], K[i1][j+1]
        q0  = fmaf(klo0, alo, q0);        q0  = fmaf(khi0, ahi, q0);
        q1  = fmaf(klo1, alo, q1);        q1  = fmaf(khi1, ahi, q1);
        mm0 = fmaf(klo0 * e0c, alo, mm0); mm0 = fmaf(khi0 * em,  ahi, mm0);
        mm1 = fmaf(klo1 * ep,  alo, mm1); mm1 = fmaf(khi1 * e0c, ahi, mm1);
        cs0 = fmaf(e0c, slo, cs0);        cs0 = fmaf(em,  shi, cs0);
        cs1 = fmaf(ep,  slo, cs1);        cs1 = fmaf(e0c, shi, cs1);
    }

    // colsum_j = b_j*q_j + STAB*sum(scl); cost = sum_j nu_j/colsum_j*(b_j*mm_j + STAB*cs_j)
    float z = 0.0f;
    if (active) {
        float col0 = fmaf(b0, q0, 1e-6f * Ssum);
        float col1 = fmaf(b1, q1, 1e-6f * Ssum);
        float in0  = fmaf(b0, mm0, 1e-6f * cs0);
        float in1  = fmaf(b1, mm1, 1e-6f * cs1);
        z = nu0 * fast_rcp(col0) * in0 + nu1 * fast_rcp(col1) * in1;
    }
    float rc = wave_sum(z);
    if (l == 0) atomicAdd(out, rc / (float)rows);
}

extern "C" void kernel_launch(void* const* d_in, const int* in_sizes, int n_in,
                              void* d_out, int out_size, void* d_ws, size_t ws_size,
                              hipStream_t stream)
{
    const float* pred   = (const float*)d_in[0];
    const int*   target = (const int*)d_in[1];
    float*       out    = (float*)d_out;
    const int    rows   = in_sizes[0] / NCLS;   // 4096

    hipLaunchKernelGGL(sk_zero_out, dim3(1), dim3(1), 0, stream, out);
    hipLaunchKernelGGL(sk_sinkhorn, dim3(rows), dim3(64), 0, stream,
                       pred, target, out, rows);
}